// Round 6
// baseline (340.579 us; speedup 1.0000x reference)
//
#include <hip/hip_runtime.h>
#include <hip/hip_bf16.h>

// Problem constants: B=4, S=2048, D=512, H=8, DK=64
// ws layout (bytes):
//   Xb    @ 0        : 8192*512 bf16        = 8388608
//   Wqkv  @ 8388608  : 1536*512 bf16        = 1572864   (BT: row n = which*512+h*64+dk, col k=d)
//   WoT   @ 9961472  : 512*512 bf16         = 524288    (row n=d, col k=h*64+dk  [permuted concat])
//   Qb    @ 10485760 : 32*2048*64 bf16      = 8388608   ([bh][s][dk], PRE-SCALED by log2(e)/8)
//   Kb    @ 18874368 : 8388608                          ([bh][s][dk])
//   VTb   @ 27262976 : 8388608                          ([bh][dk][s])
//   Oc    @ 35651584 : 8388608                          ([b][s][h*64+dk])
// total 44040192 bytes

typedef __bf16 bf16;
typedef __bf16 bf16x8 __attribute__((ext_vector_type(8)));
typedef __bf16 bf16x4 __attribute__((ext_vector_type(4)));
typedef float  f32x4  __attribute__((ext_vector_type(4)));
typedef float  f32x16 __attribute__((ext_vector_type(16)));
typedef unsigned int u32;
typedef u32 u32x4 __attribute__((ext_vector_type(4)));

#define AS1 __attribute__((address_space(1)))
#define AS3 __attribute__((address_space(3)))

__device__ __forceinline__ void async_lds16(const void* gsrc, void* ldst) {
  __builtin_amdgcn_global_load_lds((AS1 const void*)gsrc, (AS3 void*)ldst, 16, 0, 0);
}

// ---------------- converters ----------------

__global__ __launch_bounds__(256) void k_cvt_x(const float4* __restrict__ X,
                                               bf16x4* __restrict__ Xb) {
  int i = blockIdx.x * 256 + threadIdx.x;
  float4 v = X[i];
  bf16x4 o = { (bf16)v.x, (bf16)v.y, (bf16)v.z, (bf16)v.w };
  Xb[i] = o;
}

__global__ __launch_bounds__(256) void k_build_wqkv(const float* __restrict__ Wq,
                                                    const float* __restrict__ Wk,
                                                    const float* __restrict__ Wv,
                                                    bf16* __restrict__ BT) {
  int idx = blockIdx.x * 256 + threadIdx.x;     // < 1536*512
  int n = idx >> 9, d = idx & 511;
  int which = n >> 9, h = (n >> 6) & 7, dk = n & 63;
  const float* W = (which == 0) ? Wq : ((which == 1) ? Wk : Wv);
  BT[idx] = (bf16)W[((h << 9) + d) * 64 + dk];
}

// WoT[n=d][k=c], c = h*64+dk (attention O layout); Wo row = dk*8+h
__global__ __launch_bounds__(256) void k_build_wo(const float* __restrict__ Wo,
                                                  bf16* __restrict__ WoT) {
  int idx = blockIdx.x * 256 + threadIdx.x;     // < 512*512
  int d = idx >> 9, c = idx & 511;
  int h = c >> 6, dk = c & 63;
  WoT[idx] = (bf16)Wo[(((dk << 3) + h) << 9) + d];
}

// ---------------- GEMM mainloop (128x128 tile, BK=32, 4 waves) ----------------

__device__ __forceinline__ void gemm_tile(const bf16* __restrict__ A,
                                          const bf16* __restrict__ BT,
                                          int K, int m0, int n0,
                                          char* sm, f32x4 acc[4][4]) {
  const int tid = threadIdx.x;
  const int lane = tid & 63, w = tid >> 6;
  const int wm = w >> 1, wn = w & 1;
  const int lr = lane & 15, lg = lane >> 4;
  for (int k0 = 0; k0 < K; k0 += 32) {
    __syncthreads();
    #pragma unroll
    for (int i = 0; i < 2; ++i) {
      int off16 = i * 256 + tid;
      int row   = off16 >> 2;
      int colb  = (off16 & 3) << 4;
      const char* srcA = (const char*)(A  + (m0 + row) * K + k0) + colb;
      const char* srcB = (const char*)(BT + (n0 + row) * K + k0) + colb;
      async_lds16(srcA, sm +        (i * 256 + w * 64) * 16);
      async_lds16(srcB, sm + 8192 + (i * 256 + w * 64) * 16);
    }
    __syncthreads();
    bf16x8 af[4], bfr[4];
    #pragma unroll
    for (int t = 0; t < 4; ++t) {
      af[t]  = *(const bf16x8*)(sm +        ((wm * 64 + t * 16 + lr) * 32 + 8 * lg) * 2);
      bfr[t] = *(const bf16x8*)(sm + 8192 + ((wn * 64 + t * 16 + lr) * 32 + 8 * lg) * 2);
    }
    #pragma unroll
    for (int am = 0; am < 4; ++am)
      #pragma unroll
      for (int bn = 0; bn < 4; ++bn)
        acc[am][bn] = __builtin_amdgcn_mfma_f32_16x16x32_bf16(af[am], bfr[bn], acc[am][bn], 0, 0, 0);
  }
}

__global__ __launch_bounds__(256) void k_gemm_qkv(const bf16* __restrict__ A,
                                                  const bf16* __restrict__ BT,
                                                  bf16* __restrict__ Qb,
                                                  bf16* __restrict__ Kb,
                                                  bf16* __restrict__ VTb) {
  __shared__ char sm[16384];
  const int m0 = blockIdx.y * 128, n0 = blockIdx.x * 128;
  f32x4 acc[4][4];
  #pragma unroll
  for (int a = 0; a < 4; ++a)
    #pragma unroll
    for (int b = 0; b < 4; ++b) { f32x4 z = {0.f,0.f,0.f,0.f}; acc[a][b] = z; }
  gemm_tile(A, BT, 512, m0, n0, sm, acc);
  const int lane = threadIdx.x & 63, w = threadIdx.x >> 6;
  const int wm = w >> 1, wn = w & 1, lr = lane & 15, lg = lane >> 4;
  const float qsc = 0.1803368801f;  // log2(e)/sqrt(64), folded into Q
  #pragma unroll
  for (int am = 0; am < 4; ++am)
    #pragma unroll
    for (int bn = 0; bn < 4; ++bn)
      #pragma unroll
      for (int r = 0; r < 4; ++r) {
        int m = m0 + wm * 64 + am * 16 + 4 * lg + r;
        int n = n0 + wn * 64 + bn * 16 + lr;
        int b = m >> 11, s = m & 2047;
        int which = n >> 9, h = (n >> 6) & 7, dk = n & 63;
        int bh = (b << 3) + h;
        float x = acc[am][bn][r];
        if (which == 0)      Qb[((bh << 11) + s) * 64 + dk] = (bf16)(x * qsc);
        else if (which == 1) Kb[((bh << 11) + s) * 64 + dk] = (bf16)x;
        else                 VTb[((bh << 6) + dk) * 2048 + s] = (bf16)x;
      }
}

__global__ __launch_bounds__(256) void k_gemm_out(const bf16* __restrict__ A,
                                                  const bf16* __restrict__ BT,
                                                  float* __restrict__ C) {
  __shared__ char sm[16384];
  const int m0 = blockIdx.y * 128, n0 = blockIdx.x * 128;
  f32x4 acc[4][4];
  #pragma unroll
  for (int a = 0; a < 4; ++a)
    #pragma unroll
    for (int b = 0; b < 4; ++b) { f32x4 z = {0.f,0.f,0.f,0.f}; acc[a][b] = z; }
  gemm_tile(A, BT, 512, m0, n0, sm, acc);
  const int lane = threadIdx.x & 63, w = threadIdx.x >> 6;
  const int wm = w >> 1, wn = w & 1, lr = lane & 15, lg = lane >> 4;
  #pragma unroll
  for (int am = 0; am < 4; ++am)
    #pragma unroll
    for (int bn = 0; bn < 4; ++bn)
      #pragma unroll
      for (int r = 0; r < 4; ++r) {
        int m = m0 + wm * 64 + am * 16 + 4 * lg + r;
        int n = n0 + wn * 64 + bn * 16 + lr;
        C[(m << 9) + n] = acc[am][bn][r];
      }
}

// ---------------- causal flash attention, swapped-operand, 4-wave KV-split ----------------
// Block = one (bh, q-tile of 32 rows), 4 waves; wave wv handles KV tiles
// t = wv, wv+4, ... (KVBLK=64), private online-softmax state; waves 1..3
// publish (m,l,O^T) via LDS, wave 0 merges and writes.
// QK^T: mfma(A=K, B=Q) -> S^T: lane holds scores of ONE q-row (q = lane&31).
// PV:   mfma(A=V^T, B=P) -> O^T: softmax state fully lane-local.
// Q pre-scaled by log2(e)/8, so P = exp2(s - m) directly.
// C/D map (32x32): col = lane&31, row = (reg&3) + 8*(reg>>2) + 4*(lane>>5).

__global__ __launch_bounds__(256, 6) void k_attn4(const bf16* __restrict__ Qb,
                                                  const bf16* __restrict__ Kb,
                                                  const bf16* __restrict__ VTb,
                                                  bf16* __restrict__ Oc) {
  __shared__ float smO[3][32][64];   // waves 1..3 partial O^T
  __shared__ float smM[3][64], smL[3][64];
  const int tid = threadIdx.x, lane = tid & 63, wv = tid >> 6;
  const int l31 = lane & 31, hi = lane >> 5;
  const int bid = blockIdx.x;
  const int bh = bid & 31, b = bh >> 3, h = bh & 7;
  const int qt = 63 - (bid >> 5);                // longest-first dispatch
  const int q0 = qt << 5;
  const bf16* Qh = Qb  + ((size_t)bh << 17);
  const bf16* Kh = Kb  + ((size_t)bh << 17);
  const bf16* Vh = VTb + ((size_t)bh << 17);

  bf16x8 qf[4];
  #pragma unroll
  for (int kd = 0; kd < 4; ++kd)
    qf[kd] = *(const bf16x8*)(Qh + ((q0 + l31) << 6) + kd * 16 + 8 * hi);

  f32x16 o0, o1;
  #pragma unroll
  for (int r = 0; r < 16; ++r) { o0[r] = 0.f; o1[r] = 0.f; }
  float m_run = -3e38f, lsum = 0.f;

  const int NT = (qt >> 1) + 1;                  // 64-wide KV tiles

  for (int t = wv; t < NT; t += 4) {
    const int tb = t << 6;
    // K fragments first (QK depends on them), then V (latency hidden by QK+softmax)
    bf16x8 kf[8];
    #pragma unroll
    for (int j = 0; j < 2; ++j)
      #pragma unroll
      for (int kd = 0; kd < 4; ++kd)
        kf[j * 4 + kd] = *(const bf16x8*)(Kh + ((tb + (j << 5) + l31) << 6) + kd * 16 + 8 * hi);
    bf16x8 vf[2][2][2];  // [half j][dvt][ks]
    #pragma unroll
    for (int j = 0; j < 2; ++j)
      #pragma unroll
      for (int dvt = 0; dvt < 2; ++dvt)
        #pragma unroll
        for (int ks = 0; ks < 2; ++ks)
          vf[j][dvt][ks] = *(const bf16x8*)(Vh + (((dvt << 5) + l31) << 11) + tb + (j << 5) + (ks << 4) + 8 * hi);

    // QK^T: two 32-col halves
    f32x16 sA, sB;
    #pragma unroll
    for (int r = 0; r < 16; ++r) { sA[r] = 0.f; sB[r] = 0.f; }
    __builtin_amdgcn_s_setprio(1);
    #pragma unroll
    for (int kd = 0; kd < 4; ++kd)
      sA = __builtin_amdgcn_mfma_f32_32x32x16_bf16(kf[kd], qf[kd], sA, 0, 0, 0);
    #pragma unroll
    for (int kd = 0; kd < 4; ++kd)
      sB = __builtin_amdgcn_mfma_f32_32x32x16_bf16(kf[4 + kd], qf[kd], sB, 0, 0, 0);
    __builtin_amdgcn_s_setprio(0);

    // causal mask (diagonal tile only)
    if (t == NT - 1) {
      const int sg = q0 + l31;
      #pragma unroll
      for (int r = 0; r < 16; ++r) {
        int rk = tb + (r & 3) + 8 * (r >> 2) + 4 * hi;
        sA[r] = (rk > sg)      ? -1e30f : sA[r];
        sB[r] = (rk + 32 > sg) ? -1e30f : sB[r];
      }
    }
    // row max: max3-shaped tree + one cross-half exchange
    float tv[16];
    #pragma unroll
    for (int r = 0; r < 16; ++r) tv[r] = fmaxf(sA[r], sB[r]);
    float t0 = fmaxf(fmaxf(tv[0], tv[1]), tv[2]);
    float t1 = fmaxf(fmaxf(tv[3], tv[4]), tv[5]);
    float t2 = fmaxf(fmaxf(tv[6], tv[7]), tv[8]);
    float t3 = fmaxf(fmaxf(tv[9], tv[10]), tv[11]);
    float t4 = fmaxf(fmaxf(tv[12], tv[13]), tv[14]);
    float t5 = fmaxf(fmaxf(t0, t1), t2);
    float t6 = fmaxf(fmaxf(t3, t4), tv[15]);
    float tmax = fmaxf(t5, t6);
    float tms = fmaxf(tmax, __shfl_xor(tmax, 32));
    // defer-max rescale (T13, THR=8 in exp2 domain)
    if (!__all(tms <= m_run + 8.f)) {
      float mn = fmaxf(m_run, tms);
      float fac = exp2f(m_run - mn);
      #pragma unroll
      for (int r = 0; r < 16; ++r) { o0[r] *= fac; o1[r] *= fac; }
      lsum *= fac;
      m_run = mn;
    }
    // P = exp2(s - m)   (scale pre-folded into Q)
    float pA[16], pB[16];
    #pragma unroll
    for (int r = 0; r < 16; ++r) pA[r] = exp2f(sA[r] - m_run);
    #pragma unroll
    for (int r = 0; r < 16; ++r) pB[r] = exp2f(sB[r] - m_run);
    // row sum
    float sv[16];
    #pragma unroll
    for (int r = 0; r < 16; ++r) sv[r] = pA[r] + pB[r];
    #pragma unroll
    for (int st = 8; st > 0; st >>= 1)
      #pragma unroll
      for (int i = 0; i < 16; ++i) if (i < st) sv[i] += sv[i + st];
    lsum += sv[0] + __shfl_xor(sv[0], 32);

    // pack P -> bf16 pairs; permlane32_swap builds PV B-fragments in-register
    #pragma unroll
    for (int j = 0; j < 2; ++j) {
      const float* p = j ? pB : pA;
      u32 pk_[8];
      #pragma unroll
      for (int i = 0; i < 8; ++i) {
        unsigned short x = __builtin_bit_cast(unsigned short, (bf16)p[2 * i]);
        unsigned short y = __builtin_bit_cast(unsigned short, (bf16)p[2 * i + 1]);
        pk_[i] = (u32)x | ((u32)y << 16);
      }
      asm volatile("v_permlane32_swap_b32 %0, %1" : "+v"(pk_[0]), "+v"(pk_[2]));
      asm volatile("v_permlane32_swap_b32 %0, %1" : "+v"(pk_[1]), "+v"(pk_[3]));
      asm volatile("v_permlane32_swap_b32 %0, %1" : "+v"(pk_[4]), "+v"(pk_[6]));
      asm volatile("v_permlane32_swap_b32 %0, %1" : "+v"(pk_[5]), "+v"(pk_[7]));
      u32x4 w0 = { pk_[0], pk_[1], pk_[2], pk_[3] };
      u32x4 w1 = { pk_[4], pk_[5], pk_[6], pk_[7] };
      bf16x8 pb0 = __builtin_bit_cast(bf16x8, w0);
      bf16x8 pb1 = __builtin_bit_cast(bf16x8, w1);
      __builtin_amdgcn_s_setprio(1);
      o0 = __builtin_amdgcn_mfma_f32_32x32x16_bf16(vf[j][0][0], pb0, o0, 0, 0, 0);
      o0 = __builtin_amdgcn_mfma_f32_32x32x16_bf16(vf[j][0][1], pb1, o0, 0, 0, 0);
      o1 = __builtin_amdgcn_mfma_f32_32x32x16_bf16(vf[j][1][0], pb0, o1, 0, 0, 0);
      o1 = __builtin_amdgcn_mfma_f32_32x32x16_bf16(vf[j][1][1], pb1, o1, 0, 0, 0);
      __builtin_amdgcn_s_setprio(0);
    }
  }

  // ---- combine the four waves' partial states ----
  if (wv > 0) {
    #pragma unroll
    for (int r = 0; r < 16; ++r) {
      smO[wv - 1][r][lane]      = o0[r];
      smO[wv - 1][16 + r][lane] = o1[r];
    }
    smM[wv - 1][lane] = m_run;
    smL[wv - 1][lane] = lsum;
  }
  __syncthreads();
  if (wv == 0) {
    float m1 = smM[0][lane], m2 = smM[1][lane], m3 = smM[2][lane];
    float mm = fmaxf(fmaxf(m_run, m1), fmaxf(m2, m3));
    float f0 = exp2f(m_run - mm), f1 = exp2f(m1 - mm);
    float f2 = exp2f(m2 - mm),   f3 = exp2f(m3 - mm);
    float l = lsum * f0 + smL[0][lane] * f1 + smL[1][lane] * f2 + smL[2][lane] * f3;
    float rn = 1.f / l;
    const int sg = q0 + l31;
    bf16* Orow = Oc + (((size_t)((b << 11) + sg)) << 9) + (h << 6);
    #pragma unroll
    for (int g = 0; g < 4; ++g) {
      bf16x4 v0, v1;
      #pragma unroll
      for (int i = 0; i < 4; ++i) {
        int r = 4 * g + i;
        float a0 = o0[r] * f0 + smO[0][r][lane] * f1 + smO[1][r][lane] * f2 + smO[2][r][lane] * f3;
        float a1 = o1[r] * f0 + smO[0][16 + r][lane] * f1 + smO[1][16 + r][lane] * f2 + smO[2][16 + r][lane] * f3;
        v0[i] = (bf16)(a0 * rn);
        v1[i] = (bf16)(a1 * rn);
      }
      *(bf16x4*)(Orow + 4 * hi + 8 * g)      = v0;
      *(bf16x4*)(Orow + 32 + 4 * hi + 8 * g) = v1;
    }
  }
}

// ---------------- launch ----------------

extern "C" void kernel_launch(void* const* d_in, const int* in_sizes, int n_in,
                              void* d_out, int out_size, void* d_ws, size_t ws_size,
                              hipStream_t stream) {
  (void)in_sizes; (void)n_in; (void)out_size; (void)ws_size;
  const float* X  = (const float*)d_in[0];
  const float* Wq = (const float*)d_in[1];
  const float* Wk = (const float*)d_in[2];
  const float* Wv = (const float*)d_in[3];
  const float* Wo = (const float*)d_in[4];
  float* out = (float*)d_out;
  char* ws = (char*)d_ws;
  bf16* Xb   = (bf16*)(ws);
  bf16* Wqkv = (bf16*)(ws + 8388608);
  bf16* WoT  = (bf16*)(ws + 9961472);
  bf16* Qb   = (bf16*)(ws + 10485760);
  bf16* Kb   = (bf16*)(ws + 18874368);
  bf16* VTb  = (bf16*)(ws + 27262976);
  bf16* Oc   = (bf16*)(ws + 35651584);

  k_cvt_x<<<4096, 256, 0, stream>>>((const float4*)X, (bf16x4*)Xb);
  k_build_wqkv<<<3072, 256, 0, stream>>>(Wq, Wk, Wv, Wqkv);
  k_build_wo<<<1024, 256, 0, stream>>>(Wo, WoT);
  k_gemm_qkv<<<dim3(12, 64), 256, 0, stream>>>(Xb, Wqkv, Qb, Kb, VTb);
  k_attn4<<<2048, 256, 0, stream>>>(Qb, Kb, VTb, Oc);
  k_gemm_out<<<dim3(4, 64), 256, 0, stream>>>(Oc, WoT, out);
}

// Round 7
// 146.333 us; speedup vs baseline: 2.3274x; 2.3274x over previous
//
#include <hip/hip_runtime.h>
#include <hip/hip_bf16.h>

// Problem constants: B=4, S=2048, D=512, H=8, DK=64
// ws layout (bytes):
//   Xb    @ 0        : 8192*512 bf16        = 8388608
//   Wqkv  @ 8388608  : 1536*512 bf16        = 1572864   (BT: row n = which*512+h*64+dk, col k=d)
//   WoT   @ 9961472  : 512*512 bf16         = 524288    (row n=d, col k=h*64+dk  [permuted concat])
//   Qb    @ 10485760 : 32*2048*64 bf16      = 8388608   ([bh][s][dk], PRE-SCALED by log2(e)/8)
//   Kb    @ 18874368 : 8388608                          ([bh][s][dk])
//   VTb   @ 27262976 : 8388608                          ([bh][dk][s])
//   Oc    @ 35651584 : 8388608                          ([b][s][h*64+dk])
// total 44040192 bytes

typedef __bf16 bf16;
typedef __bf16 bf16x8 __attribute__((ext_vector_type(8)));
typedef __bf16 bf16x4 __attribute__((ext_vector_type(4)));
typedef float  f32x4  __attribute__((ext_vector_type(4)));
typedef float  f32x16 __attribute__((ext_vector_type(16)));
typedef unsigned int u32;
typedef u32 u32x4 __attribute__((ext_vector_type(4)));

#define AS1 __attribute__((address_space(1)))
#define AS3 __attribute__((address_space(3)))

__device__ __forceinline__ void async_lds16(const void* gsrc, void* ldst) {
  __builtin_amdgcn_global_load_lds((AS1 const void*)gsrc, (AS3 void*)ldst, 16, 0, 0);
}

// ---------------- converters ----------------

__global__ __launch_bounds__(256) void k_cvt_x(const float4* __restrict__ X,
                                               bf16x4* __restrict__ Xb) {
  int i = blockIdx.x * 256 + threadIdx.x;
  float4 v = X[i];
  bf16x4 o = { (bf16)v.x, (bf16)v.y, (bf16)v.z, (bf16)v.w };
  Xb[i] = o;
}

__global__ __launch_bounds__(256) void k_build_wqkv(const float* __restrict__ Wq,
                                                    const float* __restrict__ Wk,
                                                    const float* __restrict__ Wv,
                                                    bf16* __restrict__ BT) {
  int idx = blockIdx.x * 256 + threadIdx.x;     // < 1536*512
  int n = idx >> 9, d = idx & 511;
  int which = n >> 9, h = (n >> 6) & 7, dk = n & 63;
  const float* W = (which == 0) ? Wq : ((which == 1) ? Wk : Wv);
  BT[idx] = (bf16)W[((h << 9) + d) * 64 + dk];
}

// WoT[n=d][k=c], c = h*64+dk (attention O layout); Wo row = dk*8+h
__global__ __launch_bounds__(256) void k_build_wo(const float* __restrict__ Wo,
                                                  bf16* __restrict__ WoT) {
  int idx = blockIdx.x * 256 + threadIdx.x;     // < 512*512
  int d = idx >> 9, c = idx & 511;
  int h = c >> 6, dk = c & 63;
  WoT[idx] = (bf16)Wo[(((dk << 3) + h) << 9) + d];
}

// ---------------- GEMM mainloop (128x128 tile, BK=32, 4 waves) ----------------

__device__ __forceinline__ void gemm_tile(const bf16* __restrict__ A,
                                          const bf16* __restrict__ BT,
                                          int K, int m0, int n0,
                                          char* sm, f32x4 acc[4][4]) {
  const int tid = threadIdx.x;
  const int lane = tid & 63, w = tid >> 6;
  const int wm = w >> 1, wn = w & 1;
  const int lr = lane & 15, lg = lane >> 4;
  for (int k0 = 0; k0 < K; k0 += 32) {
    __syncthreads();
    #pragma unroll
    for (int i = 0; i < 2; ++i) {
      int off16 = i * 256 + tid;
      int row   = off16 >> 2;
      int colb  = (off16 & 3) << 4;
      const char* srcA = (const char*)(A  + (m0 + row) * K + k0) + colb;
      const char* srcB = (const char*)(BT + (n0 + row) * K + k0) + colb;
      async_lds16(srcA, sm +        (i * 256 + w * 64) * 16);
      async_lds16(srcB, sm + 8192 + (i * 256 + w * 64) * 16);
    }
    __syncthreads();
    bf16x8 af[4], bfr[4];
    #pragma unroll
    for (int t = 0; t < 4; ++t) {
      af[t]  = *(const bf16x8*)(sm +        ((wm * 64 + t * 16 + lr) * 32 + 8 * lg) * 2);
      bfr[t] = *(const bf16x8*)(sm + 8192 + ((wn * 64 + t * 16 + lr) * 32 + 8 * lg) * 2);
    }
    #pragma unroll
    for (int am = 0; am < 4; ++am)
      #pragma unroll
      for (int bn = 0; bn < 4; ++bn)
        acc[am][bn] = __builtin_amdgcn_mfma_f32_16x16x32_bf16(af[am], bfr[bn], acc[am][bn], 0, 0, 0);
  }
}

__global__ __launch_bounds__(256) void k_gemm_qkv(const bf16* __restrict__ A,
                                                  const bf16* __restrict__ BT,
                                                  bf16* __restrict__ Qb,
                                                  bf16* __restrict__ Kb,
                                                  bf16* __restrict__ VTb) {
  __shared__ char sm[16384];
  const int m0 = blockIdx.y * 128, n0 = blockIdx.x * 128;
  f32x4 acc[4][4];
  #pragma unroll
  for (int a = 0; a < 4; ++a)
    #pragma unroll
    for (int b = 0; b < 4; ++b) { f32x4 z = {0.f,0.f,0.f,0.f}; acc[a][b] = z; }
  gemm_tile(A, BT, 512, m0, n0, sm, acc);
  const int lane = threadIdx.x & 63, w = threadIdx.x >> 6;
  const int wm = w >> 1, wn = w & 1, lr = lane & 15, lg = lane >> 4;
  const float qsc = 0.1803368801f;  // log2(e)/sqrt(64), folded into Q
  #pragma unroll
  for (int am = 0; am < 4; ++am)
    #pragma unroll
    for (int bn = 0; bn < 4; ++bn)
      #pragma unroll
      for (int r = 0; r < 4; ++r) {
        int m = m0 + wm * 64 + am * 16 + 4 * lg + r;
        int n = n0 + wn * 64 + bn * 16 + lr;
        int b = m >> 11, s = m & 2047;
        int which = n >> 9, h = (n >> 6) & 7, dk = n & 63;
        int bh = (b << 3) + h;
        float x = acc[am][bn][r];
        if (which == 0)      Qb[((bh << 11) + s) * 64 + dk] = (bf16)(x * qsc);
        else if (which == 1) Kb[((bh << 11) + s) * 64 + dk] = (bf16)x;
        else                 VTb[((bh << 6) + dk) * 2048 + s] = (bf16)x;
      }
}

__global__ __launch_bounds__(256) void k_gemm_out(const bf16* __restrict__ A,
                                                  const bf16* __restrict__ BT,
                                                  float* __restrict__ C) {
  __shared__ char sm[16384];
  const int m0 = blockIdx.y * 128, n0 = blockIdx.x * 128;
  f32x4 acc[4][4];
  #pragma unroll
  for (int a = 0; a < 4; ++a)
    #pragma unroll
    for (int b = 0; b < 4; ++b) { f32x4 z = {0.f,0.f,0.f,0.f}; acc[a][b] = z; }
  gemm_tile(A, BT, 512, m0, n0, sm, acc);
  const int lane = threadIdx.x & 63, w = threadIdx.x >> 6;
  const int wm = w >> 1, wn = w & 1, lr = lane & 15, lg = lane >> 4;
  #pragma unroll
  for (int am = 0; am < 4; ++am)
    #pragma unroll
    for (int bn = 0; bn < 4; ++bn)
      #pragma unroll
      for (int r = 0; r < 4; ++r) {
        int m = m0 + wm * 64 + am * 16 + 4 * lg + r;
        int n = n0 + wn * 64 + bn * 16 + lr;
        C[(m << 9) + n] = acc[am][bn][r];
      }
}

// ---------------- causal flash attention, swapped-operand, 4-wave KV-split ----------------
// Block = one (bh, q-tile of 32 rows), 4 waves; wave wv handles KV tiles
// t = wv, wv+4, ... (KVBLK=64), private online-softmax state; waves 1..3
// publish (m,l,O^T) via LDS, wave 0 merges and writes.
// __launch_bounds__(256,3): VGPR cap ~168 >> ~120 peak-live -> NO SPILL
// (round-6 lesson: (256,6) forced VGPR=40 -> 1.25 GB scratch traffic).
// QK^T: mfma(A=K, B=Q) -> S^T: lane holds scores of ONE q-row (q = lane&31).
// PV:   mfma(A=V^T, B=P) -> O^T: softmax state fully lane-local.
// Q pre-scaled by log2(e)/8, so P = exp2(s - m) directly.
// C/D map (32x32): col = lane&31, row = (reg&3) + 8*(reg>>2) + 4*(lane>>5).

__global__ __launch_bounds__(256, 3) void k_attn4(const bf16* __restrict__ Qb,
                                                  const bf16* __restrict__ Kb,
                                                  const bf16* __restrict__ VTb,
                                                  bf16* __restrict__ Oc) {
  __shared__ float smO[3][32][64];   // waves 1..3 partial O^T
  __shared__ float smM[3][64], smL[3][64];
  const int tid = threadIdx.x, lane = tid & 63, wv = tid >> 6;
  const int l31 = lane & 31, hi = lane >> 5;
  const int bid = blockIdx.x;
  const int bh = bid & 31, b = bh >> 3, h = bh & 7;
  const int qt = 63 - (bid >> 5);                // longest-first dispatch
  const int q0 = qt << 5;
  const bf16* Qh = Qb  + ((size_t)bh << 17);
  const bf16* Kh = Kb  + ((size_t)bh << 17);
  const bf16* Vh = VTb + ((size_t)bh << 17);

  bf16x8 qf[4];
  #pragma unroll
  for (int kd = 0; kd < 4; ++kd)
    qf[kd] = *(const bf16x8*)(Qh + ((q0 + l31) << 6) + kd * 16 + 8 * hi);

  f32x16 o0, o1;
  #pragma unroll
  for (int r = 0; r < 16; ++r) { o0[r] = 0.f; o1[r] = 0.f; }
  float m_run = -3e38f, lsum = 0.f;

  const int NT = (qt >> 1) + 1;                  // 64-wide KV tiles

  for (int t = wv; t < NT; t += 4) {
    const int tb = t << 6;
    // K fragments first (QK depends on them), then V (latency hidden by QK+softmax)
    bf16x8 kf[8];
    #pragma unroll
    for (int j = 0; j < 2; ++j)
      #pragma unroll
      for (int kd = 0; kd < 4; ++kd)
        kf[j * 4 + kd] = *(const bf16x8*)(Kh + ((tb + (j << 5) + l31) << 6) + kd * 16 + 8 * hi);
    bf16x8 vf[2][2][2];  // [half j][dvt][ks]
    #pragma unroll
    for (int j = 0; j < 2; ++j)
      #pragma unroll
      for (int dvt = 0; dvt < 2; ++dvt)
        #pragma unroll
        for (int ks = 0; ks < 2; ++ks)
          vf[j][dvt][ks] = *(const bf16x8*)(Vh + (((dvt << 5) + l31) << 11) + tb + (j << 5) + (ks << 4) + 8 * hi);

    // QK^T: two 32-col halves
    f32x16 sA, sB;
    #pragma unroll
    for (int r = 0; r < 16; ++r) { sA[r] = 0.f; sB[r] = 0.f; }
    __builtin_amdgcn_s_setprio(1);
    #pragma unroll
    for (int kd = 0; kd < 4; ++kd)
      sA = __builtin_amdgcn_mfma_f32_32x32x16_bf16(kf[kd], qf[kd], sA, 0, 0, 0);
    #pragma unroll
    for (int kd = 0; kd < 4; ++kd)
      sB = __builtin_amdgcn_mfma_f32_32x32x16_bf16(kf[4 + kd], qf[kd], sB, 0, 0, 0);
    __builtin_amdgcn_s_setprio(0);

    // causal mask (diagonal tile only)
    if (t == NT - 1) {
      const int sg = q0 + l31;
      #pragma unroll
      for (int r = 0; r < 16; ++r) {
        int rk = tb + (r & 3) + 8 * (r >> 2) + 4 * hi;
        sA[r] = (rk > sg)      ? -1e30f : sA[r];
        sB[r] = (rk + 32 > sg) ? -1e30f : sB[r];
      }
    }
    // row max: max3-shaped tree + one cross-half exchange
    float tv[16];
    #pragma unroll
    for (int r = 0; r < 16; ++r) tv[r] = fmaxf(sA[r], sB[r]);
    float t0 = fmaxf(fmaxf(tv[0], tv[1]), tv[2]);
    float t1 = fmaxf(fmaxf(tv[3], tv[4]), tv[5]);
    float t2 = fmaxf(fmaxf(tv[6], tv[7]), tv[8]);
    float t3 = fmaxf(fmaxf(tv[9], tv[10]), tv[11]);
    float t4 = fmaxf(fmaxf(tv[12], tv[13]), tv[14]);
    float t5 = fmaxf(fmaxf(t0, t1), t2);
    float t6 = fmaxf(fmaxf(t3, t4), tv[15]);
    float tmax = fmaxf(t5, t6);
    float tms = fmaxf(tmax, __shfl_xor(tmax, 32));
    // defer-max rescale (T13, THR=8 in exp2 domain)
    if (!__all(tms <= m_run + 8.f)) {
      float mn = fmaxf(m_run, tms);
      float fac = exp2f(m_run - mn);
      #pragma unroll
      for (int r = 0; r < 16; ++r) { o0[r] *= fac; o1[r] *= fac; }
      lsum *= fac;
      m_run = mn;
    }
    // P = exp2(s - m)   (scale pre-folded into Q)
    float pA[16], pB[16];
    #pragma unroll
    for (int r = 0; r < 16; ++r) pA[r] = exp2f(sA[r] - m_run);
    #pragma unroll
    for (int r = 0; r < 16; ++r) pB[r] = exp2f(sB[r] - m_run);
    // row sum
    float sv[16];
    #pragma unroll
    for (int r = 0; r < 16; ++r) sv[r] = pA[r] + pB[r];
    #pragma unroll
    for (int st = 8; st > 0; st >>= 1)
      #pragma unroll
      for (int i = 0; i < 16; ++i) if (i < st) sv[i] += sv[i + st];
    lsum += sv[0] + __shfl_xor(sv[0], 32);

    // pack P -> bf16 pairs; permlane32_swap builds PV B-fragments in-register
    #pragma unroll
    for (int j = 0; j < 2; ++j) {
      const float* p = j ? pB : pA;
      u32 pk_[8];
      #pragma unroll
      for (int i = 0; i < 8; ++i) {
        unsigned short x = __builtin_bit_cast(unsigned short, (bf16)p[2 * i]);
        unsigned short y = __builtin_bit_cast(unsigned short, (bf16)p[2 * i + 1]);
        pk_[i] = (u32)x | ((u32)y << 16);
      }
      asm volatile("v_permlane32_swap_b32 %0, %1" : "+v"(pk_[0]), "+v"(pk_[2]));
      asm volatile("v_permlane32_swap_b32 %0, %1" : "+v"(pk_[1]), "+v"(pk_[3]));
      asm volatile("v_permlane32_swap_b32 %0, %1" : "+v"(pk_[4]), "+v"(pk_[6]));
      asm volatile("v_permlane32_swap_b32 %0, %1" : "+v"(pk_[5]), "+v"(pk_[7]));
      u32x4 w0 = { pk_[0], pk_[1], pk_[2], pk_[3] };
      u32x4 w1 = { pk_[4], pk_[5], pk_[6], pk_[7] };
      bf16x8 pb0 = __builtin_bit_cast(bf16x8, w0);
      bf16x8 pb1 = __builtin_bit_cast(bf16x8, w1);
      __builtin_amdgcn_s_setprio(1);
      o0 = __builtin_amdgcn_mfma_f32_32x32x16_bf16(vf[j][0][0], pb0, o0, 0, 0, 0);
      o0 = __builtin_amdgcn_mfma_f32_32x32x16_bf16(vf[j][0][1], pb1, o0, 0, 0, 0);
      o1 = __builtin_amdgcn_mfma_f32_32x32x16_bf16(vf[j][1][0], pb0, o1, 0, 0, 0);
      o1 = __builtin_amdgcn_mfma_f32_32x32x16_bf16(vf[j][1][1], pb1, o1, 0, 0, 0);
      __builtin_amdgcn_s_setprio(0);
    }
  }

  // ---- combine the four waves' partial states ----
  if (wv > 0) {
    #pragma unroll
    for (int r = 0; r < 16; ++r) {
      smO[wv - 1][r][lane]      = o0[r];
      smO[wv - 1][16 + r][lane] = o1[r];
    }
    smM[wv - 1][lane] = m_run;
    smL[wv - 1][lane] = lsum;
  }
  __syncthreads();
  if (wv == 0) {
    float m1 = smM[0][lane], m2 = smM[1][lane], m3 = smM[2][lane];
    float mm = fmaxf(fmaxf(m_run, m1), fmaxf(m2, m3));
    float f0 = exp2f(m_run - mm), f1 = exp2f(m1 - mm);
    float f2 = exp2f(m2 - mm),   f3 = exp2f(m3 - mm);
    float l = lsum * f0 + smL[0][lane] * f1 + smL[1][lane] * f2 + smL[2][lane] * f3;
    float rn = 1.f / l;
    const int sg = q0 + l31;
    bf16* Orow = Oc + (((size_t)((b << 11) + sg)) << 9) + (h << 6);
    #pragma unroll
    for (int g = 0; g < 4; ++g) {
      bf16x4 v0, v1;
      #pragma unroll
      for (int i = 0; i < 4; ++i) {
        int r = 4 * g + i;
        float a0 = o0[r] * f0 + smO[0][r][lane] * f1 + smO[1][r][lane] * f2 + smO[2][r][lane] * f3;
        float a1 = o1[r] * f0 + smO[0][16 + r][lane] * f1 + smO[1][16 + r][lane] * f2 + smO[2][16 + r][lane] * f3;
        v0[i] = (bf16)(a0 * rn);
        v1[i] = (bf16)(a1 * rn);
      }
      *(bf16x4*)(Orow + 4 * hi + 8 * g)      = v0;
      *(bf16x4*)(Orow + 32 + 4 * hi + 8 * g) = v1;
    }
  }
}

// ---------------- launch ----------------

extern "C" void kernel_launch(void* const* d_in, const int* in_sizes, int n_in,
                              void* d_out, int out_size, void* d_ws, size_t ws_size,
                              hipStream_t stream) {
  (void)in_sizes; (void)n_in; (void)out_size; (void)ws_size;
  const float* X  = (const float*)d_in[0];
  const float* Wq = (const float*)d_in[1];
  const float* Wk = (const float*)d_in[2];
  const float* Wv = (const float*)d_in[3];
  const float* Wo = (const float*)d_in[4];
  float* out = (float*)d_out;
  char* ws = (char*)d_ws;
  bf16* Xb   = (bf16*)(ws);
  bf16* Wqkv = (bf16*)(ws + 8388608);
  bf16* WoT  = (bf16*)(ws + 9961472);
  bf16* Qb   = (bf16*)(ws + 10485760);
  bf16* Kb   = (bf16*)(ws + 18874368);
  bf16* VTb  = (bf16*)(ws + 27262976);
  bf16* Oc   = (bf16*)(ws + 35651584);

  k_cvt_x<<<4096, 256, 0, stream>>>((const float4*)X, (bf16x4*)Xb);
  k_build_wqkv<<<3072, 256, 0, stream>>>(Wq, Wk, Wv, Wqkv);
  k_build_wo<<<1024, 256, 0, stream>>>(Wo, WoT);
  k_gemm_qkv<<<dim3(12, 64), 256, 0, stream>>>(Xb, Wqkv, Qb, Kb, VTb);
  k_attn4<<<2048, 256, 0, stream>>>(Qb, Kb, VTb, Oc);
  k_gemm_out<<<dim3(4, 64), 256, 0, stream>>>(Oc, WoT, out);
}

// Round 8
// 144.373 us; speedup vs baseline: 2.3590x; 1.0136x over previous
//
#include <hip/hip_runtime.h>
#include <hip/hip_bf16.h>

// Problem constants: B=4, S=2048, D=512, H=8, DK=64
// ws layout (bytes):
//   Xb    @ 0        : 8192*512 bf16        = 8388608
//   Wqkv  @ 8388608  : 1536*512 bf16        = 1572864   (BT: row n = which*512+h*64+dk, col k=d)
//   WoT   @ 9961472  : 512*512 bf16         = 524288    (row n=d, col k=h*64+dk  [permuted concat])
//   Qb    @ 10485760 : 32*2048*64 bf16      = 8388608   ([bh][s][dk], PRE-SCALED by log2(e)/8)
//   Kb    @ 18874368 : 8388608                          ([bh][s][dk])
//   VTb   @ 27262976 : 8388608                          ([bh][dk][s])
//   Oc    @ 35651584 : 8388608                          ([b][s][h*64+dk])
// total 44040192 bytes

typedef __bf16 bf16;
typedef __bf16 bf16x8 __attribute__((ext_vector_type(8)));
typedef __bf16 bf16x4 __attribute__((ext_vector_type(4)));
typedef __bf16 bf16x2 __attribute__((ext_vector_type(2)));
typedef float  f32x4  __attribute__((ext_vector_type(4)));
typedef float  f32x16 __attribute__((ext_vector_type(16)));
typedef unsigned int u32;
typedef u32 u32x4 __attribute__((ext_vector_type(4)));

#define AS1 __attribute__((address_space(1)))
#define AS3 __attribute__((address_space(3)))

__device__ __forceinline__ void async_lds16(const void* gsrc, void* ldst) {
  __builtin_amdgcn_global_load_lds((AS1 const void*)gsrc, (AS3 void*)ldst, 16, 0, 0);
}

// single-instruction exp2 (args are bounded: <= THR=8 after max-subtract; -1e30 -> 0)
__device__ __forceinline__ float fexp2(float x) {
  float r;
  asm("v_exp_f32 %0, %1" : "=v"(r) : "v"(x));
  return r;
}

// ---------------- converters ----------------

__global__ __launch_bounds__(256) void k_cvt_x(const float4* __restrict__ X,
                                               bf16x4* __restrict__ Xb) {
  int i = blockIdx.x * 256 + threadIdx.x;
  float4 v = X[i];
  bf16x4 o = { (bf16)v.x, (bf16)v.y, (bf16)v.z, (bf16)v.w };
  Xb[i] = o;
}

__global__ __launch_bounds__(256) void k_build_wqkv(const float* __restrict__ Wq,
                                                    const float* __restrict__ Wk,
                                                    const float* __restrict__ Wv,
                                                    bf16* __restrict__ BT) {
  int idx = blockIdx.x * 256 + threadIdx.x;     // < 1536*512
  int n = idx >> 9, d = idx & 511;
  int which = n >> 9, h = (n >> 6) & 7, dk = n & 63;
  const float* W = (which == 0) ? Wq : ((which == 1) ? Wk : Wv);
  BT[idx] = (bf16)W[((h << 9) + d) * 64 + dk];
}

// WoT[n=d][k=c], c = h*64+dk (attention O layout); Wo row = dk*8+h
__global__ __launch_bounds__(256) void k_build_wo(const float* __restrict__ Wo,
                                                  bf16* __restrict__ WoT) {
  int idx = blockIdx.x * 256 + threadIdx.x;     // < 512*512
  int d = idx >> 9, c = idx & 511;
  int h = c >> 6, dk = c & 63;
  WoT[idx] = (bf16)Wo[(((dk << 3) + h) << 9) + d];
}

// ---------------- GEMM mainloop (128x128 tile, BK=32, 4 waves) ----------------

__device__ __forceinline__ void gemm_tile(const bf16* __restrict__ A,
                                          const bf16* __restrict__ BT,
                                          int K, int m0, int n0,
                                          char* sm, f32x4 acc[4][4]) {
  const int tid = threadIdx.x;
  const int lane = tid & 63, w = tid >> 6;
  const int wm = w >> 1, wn = w & 1;
  const int lr = lane & 15, lg = lane >> 4;
  for (int k0 = 0; k0 < K; k0 += 32) {
    __syncthreads();
    #pragma unroll
    for (int i = 0; i < 2; ++i) {
      int off16 = i * 256 + tid;
      int row   = off16 >> 2;
      int colb  = (off16 & 3) << 4;
      const char* srcA = (const char*)(A  + (m0 + row) * K + k0) + colb;
      const char* srcB = (const char*)(BT + (n0 + row) * K + k0) + colb;
      async_lds16(srcA, sm +        (i * 256 + w * 64) * 16);
      async_lds16(srcB, sm + 8192 + (i * 256 + w * 64) * 16);
    }
    __syncthreads();
    bf16x8 af[4], bfr[4];
    #pragma unroll
    for (int t = 0; t < 4; ++t) {
      af[t]  = *(const bf16x8*)(sm +        ((wm * 64 + t * 16 + lr) * 32 + 8 * lg) * 2);
      bfr[t] = *(const bf16x8*)(sm + 8192 + ((wn * 64 + t * 16 + lr) * 32 + 8 * lg) * 2);
    }
    #pragma unroll
    for (int am = 0; am < 4; ++am)
      #pragma unroll
      for (int bn = 0; bn < 4; ++bn)
        acc[am][bn] = __builtin_amdgcn_mfma_f32_16x16x32_bf16(af[am], bfr[bn], acc[am][bn], 0, 0, 0);
  }
}

__global__ __launch_bounds__(256) void k_gemm_qkv(const bf16* __restrict__ A,
                                                  const bf16* __restrict__ BT,
                                                  bf16* __restrict__ Qb,
                                                  bf16* __restrict__ Kb,
                                                  bf16* __restrict__ VTb) {
  __shared__ char sm[16384];
  const int m0 = blockIdx.y * 128, n0 = blockIdx.x * 128;
  f32x4 acc[4][4];
  #pragma unroll
  for (int a = 0; a < 4; ++a)
    #pragma unroll
    for (int b = 0; b < 4; ++b) { f32x4 z = {0.f,0.f,0.f,0.f}; acc[a][b] = z; }
  gemm_tile(A, BT, 512, m0, n0, sm, acc);
  const int lane = threadIdx.x & 63, w = threadIdx.x >> 6;
  const int wm = w >> 1, wn = w & 1, lr = lane & 15, lg = lane >> 4;
  const float qsc = 0.1803368801f;  // log2(e)/sqrt(64), folded into Q
  #pragma unroll
  for (int am = 0; am < 4; ++am)
    #pragma unroll
    for (int bn = 0; bn < 4; ++bn)
      #pragma unroll
      for (int r = 0; r < 4; ++r) {
        int m = m0 + wm * 64 + am * 16 + 4 * lg + r;
        int n = n0 + wn * 64 + bn * 16 + lr;
        int b = m >> 11, s = m & 2047;
        int which = n >> 9, h = (n >> 6) & 7, dk = n & 63;
        int bh = (b << 3) + h;
        float x = acc[am][bn][r];
        if (which == 0)      Qb[((bh << 11) + s) * 64 + dk] = (bf16)(x * qsc);
        else if (which == 1) Kb[((bh << 11) + s) * 64 + dk] = (bf16)x;
        else                 VTb[((bh << 6) + dk) * 2048 + s] = (bf16)x;
      }
}

__global__ __launch_bounds__(256) void k_gemm_out(const bf16* __restrict__ A,
                                                  const bf16* __restrict__ BT,
                                                  float* __restrict__ C) {
  __shared__ char sm[16384];
  const int m0 = blockIdx.y * 128, n0 = blockIdx.x * 128;
  f32x4 acc[4][4];
  #pragma unroll
  for (int a = 0; a < 4; ++a)
    #pragma unroll
    for (int b = 0; b < 4; ++b) { f32x4 z = {0.f,0.f,0.f,0.f}; acc[a][b] = z; }
  gemm_tile(A, BT, 512, m0, n0, sm, acc);
  const int lane = threadIdx.x & 63, w = threadIdx.x >> 6;
  const int wm = w >> 1, wn = w & 1, lr = lane & 15, lg = lane >> 4;
  #pragma unroll
  for (int am = 0; am < 4; ++am)
    #pragma unroll
    for (int bn = 0; bn < 4; ++bn)
      #pragma unroll
      for (int r = 0; r < 4; ++r) {
        int m = m0 + wm * 64 + am * 16 + 4 * lg + r;
        int n = n0 + wn * 64 + bn * 16 + lr;
        C[(m << 9) + n] = acc[am][bn][r];
      }
}

// ---------------- causal flash attention, swapped-operand, 4-wave KV-split ----------------
// Block = one (bh, q-tile of 32 rows), 4 waves; wave wv handles KV tiles
// t = wv, wv+4, ... (KVBLK=64), private online-softmax state; waves 1..3
// publish (m,l,O^T) via LDS, wave 0 merges and writes.
// Register discipline (round-7 lesson: combined VGPR+AGPR ~200 capped us at
// 2 waves/SIMD): V fragments are loaded AFTER softmax so K-frags and V-frags
// are never simultaneously live. exp = 1x v_exp_f32 (asm). Pack via bf16x2
// (compiler emits v_cvt_pk_bf16_f32).
// QK^T: mfma(A=K, B=Q) -> S^T: lane holds scores of ONE q-row (q = lane&31).
// PV:   mfma(A=V^T, B=P) -> O^T: softmax state fully lane-local.
// Q pre-scaled by log2(e)/8, so P = exp2(s - m) directly.
// C/D map (32x32): col = lane&31, row = (reg&3) + 8*(reg>>2) + 4*(lane>>5).

__global__ __launch_bounds__(256, 3) void k_attn4(const bf16* __restrict__ Qb,
                                                  const bf16* __restrict__ Kb,
                                                  const bf16* __restrict__ VTb,
                                                  bf16* __restrict__ Oc) {
  __shared__ float smO[3][32][64];   // waves 1..3 partial O^T
  __shared__ float smM[3][64], smL[3][64];
  const int tid = threadIdx.x, lane = tid & 63, wv = tid >> 6;
  const int l31 = lane & 31, hi = lane >> 5;
  const int bid = blockIdx.x;
  const int bh = bid & 31, b = bh >> 3, h = bh & 7;
  const int qt = 63 - (bid >> 5);                // longest-first dispatch
  const int q0 = qt << 5;
  const bf16* Qh = Qb  + ((size_t)bh << 17);
  const bf16* Kh = Kb  + ((size_t)bh << 17);
  const bf16* Vh = VTb + ((size_t)bh << 17);

  bf16x8 qf[4];
  #pragma unroll
  for (int kd = 0; kd < 4; ++kd)
    qf[kd] = *(const bf16x8*)(Qh + ((q0 + l31) << 6) + kd * 16 + 8 * hi);

  f32x16 o0, o1;
  #pragma unroll
  for (int r = 0; r < 16; ++r) { o0[r] = 0.f; o1[r] = 0.f; }
  float m_run = -3e38f, lsum = 0.f;

  const int NT = (qt >> 1) + 1;                  // 64-wide KV tiles

  for (int t = wv; t < NT; t += 4) {
    const int tb = t << 6;
    // K fragments (QK depends on them)
    bf16x8 kf[8];
    #pragma unroll
    for (int j = 0; j < 2; ++j)
      #pragma unroll
      for (int kd = 0; kd < 4; ++kd)
        kf[j * 4 + kd] = *(const bf16x8*)(Kh + ((tb + (j << 5) + l31) << 6) + kd * 16 + 8 * hi);

    // QK^T: two 32-col halves
    f32x16 sA, sB;
    #pragma unroll
    for (int r = 0; r < 16; ++r) { sA[r] = 0.f; sB[r] = 0.f; }
    __builtin_amdgcn_s_setprio(1);
    #pragma unroll
    for (int kd = 0; kd < 4; ++kd)
      sA = __builtin_amdgcn_mfma_f32_32x32x16_bf16(kf[kd], qf[kd], sA, 0, 0, 0);
    #pragma unroll
    for (int kd = 0; kd < 4; ++kd)
      sB = __builtin_amdgcn_mfma_f32_32x32x16_bf16(kf[4 + kd], qf[kd], sB, 0, 0, 0);
    __builtin_amdgcn_s_setprio(0);

    // causal mask (diagonal tile only)
    if (t == NT - 1) {
      const int sg = q0 + l31;
      #pragma unroll
      for (int r = 0; r < 16; ++r) {
        int rk = tb + (r & 3) + 8 * (r >> 2) + 4 * hi;
        sA[r] = (rk > sg)      ? -1e30f : sA[r];
        sB[r] = (rk + 32 > sg) ? -1e30f : sB[r];
      }
    }
    // row max: max3-shaped tree + one cross-half exchange
    float tv[16];
    #pragma unroll
    for (int r = 0; r < 16; ++r) tv[r] = fmaxf(sA[r], sB[r]);
    float t0 = fmaxf(fmaxf(tv[0], tv[1]), tv[2]);
    float t1 = fmaxf(fmaxf(tv[3], tv[4]), tv[5]);
    float t2 = fmaxf(fmaxf(tv[6], tv[7]), tv[8]);
    float t3 = fmaxf(fmaxf(tv[9], tv[10]), tv[11]);
    float t4 = fmaxf(fmaxf(tv[12], tv[13]), tv[14]);
    float t5 = fmaxf(fmaxf(t0, t1), t2);
    float t6 = fmaxf(fmaxf(t3, t4), tv[15]);
    float tmax = fmaxf(t5, t6);
    float tms = fmaxf(tmax, __shfl_xor(tmax, 32));
    // defer-max rescale (T13, THR=8 in exp2 domain)
    if (!__all(tms <= m_run + 8.f)) {
      float mn = fmaxf(m_run, tms);
      float fac = fexp2(m_run - mn);
      #pragma unroll
      for (int r = 0; r < 16; ++r) { o0[r] *= fac; o1[r] *= fac; }
      lsum *= fac;
      m_run = mn;
    }
    // P = exp2(s - m)   (scale pre-folded into Q; single v_exp_f32 each)
    float pA[16], pB[16];
    #pragma unroll
    for (int r = 0; r < 16; ++r) pA[r] = fexp2(sA[r] - m_run);
    #pragma unroll
    for (int r = 0; r < 16; ++r) pB[r] = fexp2(sB[r] - m_run);
    // row sum
    float sv[16];
    #pragma unroll
    for (int r = 0; r < 16; ++r) sv[r] = pA[r] + pB[r];
    #pragma unroll
    for (int st = 8; st > 0; st >>= 1)
      #pragma unroll
      for (int i = 0; i < 16; ++i) if (i < st) sv[i] += sv[i + st];
    lsum += sv[0] + __shfl_xor(sv[0], 32);

    // V fragments now (K-frags dead; pack phase covers load latency)
    bf16x8 vf[2][2][2];  // [half j][dvt][ks]
    #pragma unroll
    for (int j = 0; j < 2; ++j)
      #pragma unroll
      for (int dvt = 0; dvt < 2; ++dvt)
        #pragma unroll
        for (int ks = 0; ks < 2; ++ks)
          vf[j][dvt][ks] = *(const bf16x8*)(Vh + (((dvt << 5) + l31) << 11) + tb + (j << 5) + (ks << 4) + 8 * hi);

    // pack P -> bf16 pairs (cvt_pk); permlane32_swap builds PV B-fragments
    #pragma unroll
    for (int j = 0; j < 2; ++j) {
      const float* p = j ? pB : pA;
      u32 pk_[8];
      #pragma unroll
      for (int i = 0; i < 8; ++i) {
        bf16x2 pr = { (bf16)p[2 * i], (bf16)p[2 * i + 1] };
        pk_[i] = __builtin_bit_cast(u32, pr);
      }
      asm volatile("v_permlane32_swap_b32 %0, %1" : "+v"(pk_[0]), "+v"(pk_[2]));
      asm volatile("v_permlane32_swap_b32 %0, %1" : "+v"(pk_[1]), "+v"(pk_[3]));
      asm volatile("v_permlane32_swap_b32 %0, %1" : "+v"(pk_[4]), "+v"(pk_[6]));
      asm volatile("v_permlane32_swap_b32 %0, %1" : "+v"(pk_[5]), "+v"(pk_[7]));
      u32x4 w0 = { pk_[0], pk_[1], pk_[2], pk_[3] };
      u32x4 w1 = { pk_[4], pk_[5], pk_[6], pk_[7] };
      bf16x8 pb0 = __builtin_bit_cast(bf16x8, w0);
      bf16x8 pb1 = __builtin_bit_cast(bf16x8, w1);
      __builtin_amdgcn_s_setprio(1);
      o0 = __builtin_amdgcn_mfma_f32_32x32x16_bf16(vf[j][0][0], pb0, o0, 0, 0, 0);
      o0 = __builtin_amdgcn_mfma_f32_32x32x16_bf16(vf[j][0][1], pb1, o0, 0, 0, 0);
      o1 = __builtin_amdgcn_mfma_f32_32x32x16_bf16(vf[j][1][0], pb0, o1, 0, 0, 0);
      o1 = __builtin_amdgcn_mfma_f32_32x32x16_bf16(vf[j][1][1], pb1, o1, 0, 0, 0);
      __builtin_amdgcn_s_setprio(0);
    }
  }

  // ---- combine the four waves' partial states ----
  if (wv > 0) {
    #pragma unroll
    for (int r = 0; r < 16; ++r) {
      smO[wv - 1][r][lane]      = o0[r];
      smO[wv - 1][16 + r][lane] = o1[r];
    }
    smM[wv - 1][lane] = m_run;
    smL[wv - 1][lane] = lsum;
  }
  __syncthreads();
  if (wv == 0) {
    float m1 = smM[0][lane], m2 = smM[1][lane], m3 = smM[2][lane];
    float mm = fmaxf(fmaxf(m_run, m1), fmaxf(m2, m3));
    float f0 = fexp2(m_run - mm), f1 = fexp2(m1 - mm);
    float f2 = fexp2(m2 - mm),   f3 = fexp2(m3 - mm);
    float l = lsum * f0 + smL[0][lane] * f1 + smL[1][lane] * f2 + smL[2][lane] * f3;
    float rn = 1.f / l;
    const int sg = q0 + l31;
    bf16* Orow = Oc + (((size_t)((b << 11) + sg)) << 9) + (h << 6);
    #pragma unroll
    for (int g = 0; g < 4; ++g) {
      bf16x4 v0, v1;
      #pragma unroll
      for (int i = 0; i < 4; ++i) {
        int r = 4 * g + i;
        float a0 = o0[r] * f0 + smO[0][r][lane] * f1 + smO[1][r][lane] * f2 + smO[2][r][lane] * f3;
        float a1 = o1[r] * f0 + smO[0][16 + r][lane] * f1 + smO[1][16 + r][lane] * f2 + smO[2][16 + r][lane] * f3;
        v0[i] = (bf16)(a0 * rn);
        v1[i] = (bf16)(a1 * rn);
      }
      *(bf16x4*)(Orow + 4 * hi + 8 * g)      = v0;
      *(bf16x4*)(Orow + 32 + 4 * hi + 8 * g) = v1;
    }
  }
}

// ---------------- launch ----------------

extern "C" void kernel_launch(void* const* d_in, const int* in_sizes, int n_in,
                              void* d_out, int out_size, void* d_ws, size_t ws_size,
                              hipStream_t stream) {
  (void)in_sizes; (void)n_in; (void)out_size; (void)ws_size;
  const float* X  = (const float*)d_in[0];
  const float* Wq = (const float*)d_in[1];
  const float* Wk = (const float*)d_in[2];
  const float* Wv = (const float*)d_in[3];
  const float* Wo = (const float*)d_in[4];
  float* out = (float*)d_out;
  char* ws = (char*)d_ws;
  bf16* Xb   = (bf16*)(ws);
  bf16* Wqkv = (bf16*)(ws + 8388608);
  bf16* WoT  = (bf16*)(ws + 9961472);
  bf16* Qb   = (bf16*)(ws + 10485760);
  bf16* Kb   = (bf16*)(ws + 18874368);
  bf16* VTb  = (bf16*)(ws + 27262976);
  bf16* Oc   = (bf16*)(ws + 35651584);

  k_cvt_x<<<4096, 256, 0, stream>>>((const float4*)X, (bf16x4*)Xb);
  k_build_wqkv<<<3072, 256, 0, stream>>>(Wq, Wk, Wv, Wqkv);
  k_build_wo<<<1024, 256, 0, stream>>>(Wo, WoT);
  k_gemm_qkv<<<dim3(12, 64), 256, 0, stream>>>(Xb, Wqkv, Qb, Kb, VTb);
  k_attn4<<<2048, 256, 0, stream>>>(Qb, Kb, VTb, Oc);
  k_gemm_out<<<dim3(4, 64), 256, 0, stream>>>(Oc, WoT, out);
}